// Round 2
// baseline (898.719 us; speedup 1.0000x reference)
//
#include <hip/hip_runtime.h>
#include <math.h>

#define NQn 100000
#define NKVn 100000
#define NEn 2000000
// D=64, H=4, F=16

// ---------------- zero-init (ws is poisoned 0xAA before every call) --------
__global__ void zero_kernel(float4* __restrict__ p, int n4) {
    int i = blockIdx.x * blockDim.x + threadIdx.x;
    int stride = gridDim.x * blockDim.x;
    for (; i < n4; i += stride) p[i] = make_float4(0.f, 0.f, 0.f, 0.f);
}

// ---------------- projection: out[r, 0:NC] = x[r, 0:64] @ W[64, NC] --------
// wave per row; lane c owns output col c (and c+64 when NC==128).
template<int NC>
__global__ void proj_kernel(const float* __restrict__ x, const float* __restrict__ W,
                            float* __restrict__ out, int nrows) {
    __shared__ float Wl[64 * NC];
    for (int i = threadIdx.x; i < 64 * NC; i += blockDim.x) Wl[i] = W[i];
    __syncthreads();
    const int lane = threadIdx.x & 63;
    const int wid  = blockIdx.x * (blockDim.x >> 6) + (threadIdx.x >> 6);
    const int nw   = gridDim.x * (blockDim.x >> 6);
    for (int r = wid; r < nrows; r += nw) {
        float xv = x[(size_t)r * 64 + lane];           // coalesced 256B row
        float acc0 = 0.f, acc1 = 0.f;
        #pragma unroll
        for (int k = 0; k < 64; ++k) {
            float xk = __shfl(xv, k, 64);              // broadcast x[r,k]
            acc0 += xk * Wl[k * NC + lane];
            if (NC == 128) acc1 += xk * Wl[k * NC + lane + 64];
        }
        out[(size_t)r * NC + lane] = acc0;
        if (NC == 128) out[(size_t)r * NC + lane + 64] = acc1;
    }
}

// ---------------- edge pass: score -> exp -> atomic scatter ----------------
// wave per edge; lane l = head (l>>4), dim (l&15).
__global__ void edge_kernel(const int* __restrict__ t, const int* __restrict__ s,
                            const float* __restrict__ q, const float* __restrict__ kvb,
                            float* __restrict__ acc, float* __restrict__ ssum) {
    const int lane = threadIdx.x & 63;
    const int wid  = blockIdx.x * (blockDim.x >> 6) + (threadIdx.x >> 6);
    const int nw   = gridDim.x * (blockDim.x >> 6);
    for (int e = wid; e < NEn; e += nw) {
        int ti = t[e], si = s[e];
        float qv = q[(size_t)ti * 64 + lane];
        float kk = kvb[(size_t)si * 128 + lane];
        float p = qv * kk;
        // reduce over the 16 lanes of this head group
        p += __shfl_xor(p, 8, 64);
        p += __shfl_xor(p, 4, 64);
        p += __shfl_xor(p, 2, 64);
        p += __shfl_xor(p, 1, 64);
        float ex = __expf(p * 0.25f);                  // /sqrt(F), F=16
        float vv = kvb[(size_t)si * 128 + 64 + lane];
        atomicAdd(&acc[(size_t)ti * 64 + lane], ex * vv);
        if ((lane & 15) == 0) atomicAdd(&ssum[(size_t)ti * 4 + (lane >> 4)], ex);
    }
}

// ---------------- epilogue: normalize + @ Wo + bo --------------------------
__global__ void out_kernel(const float* __restrict__ acc, const float* __restrict__ ssum,
                           const float* __restrict__ Wo, const float* __restrict__ bo,
                           float* __restrict__ out) {
    __shared__ float Wl[64 * 64];
    for (int i = threadIdx.x; i < 64 * 64; i += blockDim.x) Wl[i] = Wo[i];
    __syncthreads();
    const int lane = threadIdx.x & 63;
    const int wid  = blockIdx.x * (blockDim.x >> 6) + (threadIdx.x >> 6);
    const int nw   = gridDim.x * (blockDim.x >> 6);
    const float b = bo[lane];
    for (int r = wid; r < NQn; r += nw) {
        float a  = acc[(size_t)r * 64 + lane];
        float su = ssum[(size_t)r * 4 + (lane >> 4)];
        float val = (su > 0.f) ? a / su : 0.f;         // empty segment -> 0
        float o = b;
        #pragma unroll
        for (int k = 0; k < 64; ++k)
            o += __shfl(val, k, 64) * Wl[k * 64 + lane];
        out[(size_t)r * 64 + lane] = o;
    }
}

extern "C" void kernel_launch(void* const* d_in, const int* in_sizes, int n_in,
                              void* d_out, int out_size, void* d_ws, size_t ws_size,
                              hipStream_t stream) {
    const float* input = (const float*)d_in[0];
    const float* other = (const float*)d_in[1];
    const int*   t     = (const int*)  d_in[2];
    const int*   s     = (const int*)  d_in[3];
    const float* Wq    = (const float*)d_in[4];
    const float* Wkv   = (const float*)d_in[5];
    const float* Wo    = (const float*)d_in[6];
    const float* bo    = (const float*)d_in[7];
    float* out = (float*)d_out;

    float* ws   = (float*)d_ws;
    float* q    = ws;                               // NQ*64
    float* kvb  = q   + (size_t)NQn * 64;           // NKV*128 (k | v)
    float* acc  = kvb + (size_t)NKVn * 128;         // NQ*64
    float* ssum = acc + (size_t)NQn * 64;           // NQ*4

    // zero the atomic accumulators (acc + ssum are contiguous)
    int n4 = (NQn * 64 + NQn * 4) / 4;
    zero_kernel<<<2048, 256, 0, stream>>>((float4*)acc, n4);

    proj_kernel<64> <<<1024, 256, 0, stream>>>(input, Wq,  q,   NQn);
    proj_kernel<128><<<1024, 256, 0, stream>>>(other, Wkv, kvb, NKVn);
    edge_kernel     <<<4096, 256, 0, stream>>>(t, s, q, kvb, acc, ssum);
    out_kernel      <<<1024, 256, 0, stream>>>(acc, ssum, Wo, bo, out);
}